// Round 7
// baseline (615.010 us; speedup 1.0000x reference)
//
#include <hip/hip_runtime.h>
#include <math.h>

#define DDIM 64
#define BUCKET 1024             // nodes per binning bucket
#define SUBR 128                // nodes per csr/degc subrange
#define LRSHIFT 17              // packed: col [0,17), lrow [17,27), val [32,64)
#define CMASK 0x1FFFF
#define LRMASK 0x3FF
#define NBLK 512
#define TPB_BIN 512
#define MAXNB 128               // max buckets (NB = ceil(100000/1024) = 98)

typedef unsigned long long ull;

__device__ inline unsigned int pack_bf16x2(float lo, float hi) {
    unsigned int a = __float_as_uint(lo);
    unsigned int b = __float_as_uint(hi);
    a = (a + 0x7fffu + ((a >> 16) & 1u)) >> 16;          // RNE
    b = (b + 0x7fffu + ((b >> 16) & 1u)) & 0xffff0000u;  // RNE, keep high
    return a | b;
}

// ---- init global fill counters (cacheline-padded: stride 16 ints) ----
__global__ void init_fill_kernel(int* __restrict__ gfill_r, int* __restrict__ gfill_c,
                                 int NB, int cap) {
    int k = blockIdx.x * blockDim.x + threadIdx.x;
    if (k < NB) {
        gfill_r[k * 16] = k * cap;
        gfill_c[k * 16] = k * cap;
    }
}

// ---- fused binning with per-wave privatized histograms ----
__global__ __launch_bounds__(TPB_BIN)
void binning_kernel(const int* __restrict__ erow, const int* __restrict__ ecol,
                    const float* __restrict__ evals,
                    int* __restrict__ gfill_r, int* __restrict__ gfill_c,
                    ull* __restrict__ br, int2* __restrict__ bc,
                    int E, int NB, int chunk) {
    __shared__ int hr[8][MAXNB];
    __shared__ int hc[8][MAXNB];
    int t = threadIdx.x;
    int wv = t >> 6;
    for (int k = t; k < 8 * MAXNB; k += TPB_BIN) { (&hr[0][0])[k] = 0; (&hc[0][0])[k] = 0; }
    __syncthreads();
    int lo = blockIdx.x * chunk;
    int hi = min(E, lo + chunk);
    // phase 1: per-wave count
    for (int i = lo + t; i < hi; i += TPB_BIN) {
        atomicAdd(&hr[wv][erow[i] >> 10], 1);
        atomicAdd(&hc[wv][ecol[i] >> 10], 1);
    }
    __syncthreads();
    // phase 2: reserve once per (block,bucket); hand each wave a private base
    if (t < NB) {
        int sr = 0, sc = 0;
        #pragma unroll
        for (int w2 = 0; w2 < 8; w2++) { sr += hr[w2][t]; sc += hc[w2][t]; }
        int basr = atomicAdd(&gfill_r[t * 16], sr);
        int basc = atomicAdd(&gfill_c[t * 16], sc);
        #pragma unroll
        for (int w2 = 0; w2 < 8; w2++) {
            int a = hr[w2][t]; hr[w2][t] = basr; basr += a;
            int b = hc[w2][t]; hc[w2][t] = basc; basc += b;
        }
    }
    __syncthreads();
    // phase 3: place (wave-local fill atomics; chunk re-read is L2-hot)
    for (int i = lo + t; i < hi; i += TPB_BIN) {
        int r = erow[i];
        int c = ecol[i];
        float v = evals[i];
        int pos = atomicAdd(&hr[wv][r >> 10], 1);
        br[pos] = ((ull)__float_as_uint(v) << 32)
                | ((ull)(r & 1023) << LRSHIFT) | (unsigned)c;
        int pos2 = atomicAdd(&hc[wv][c >> 10], 1);
        int2 pc;
        pc.x = c & 1023;
        pc.y = __float_as_int(v);
        bc[pos2] = pc;
    }
}

// ---- col degrees -> inv_c; one block per 128-col subrange (8 blocks/bucket) ----
__global__ __launch_bounds__(256)
void degc_kernel(const int2* __restrict__ bc, const int* __restrict__ gfill_c,
                 float* __restrict__ inv_c, int N, int cap) {
    __shared__ float dsum[SUBR];
    int q = blockIdx.x;
    int b = q >> 3, sub = q & 7;
    int t = threadIdx.x;
    if (t < SUBR) dsum[t] = 0.0f;
    __syncthreads();
    int s = b * cap, e = gfill_c[b * 16];
    int lo = sub * SUBR;
    for (int i = s + t; i < e; i += 256) {
        int2 p = bc[i];
        int d = p.x - lo;
        if ((unsigned)d < SUBR) atomicAdd(&dsum[d], __int_as_float(p.y));
    }
    __syncthreads();
    int node = q * SUBR + t;
    if (t < SUBR && node < N) inv_c[node] = 1.0f / (sqrtf(dsum[t]) + 1e-8f);
}

// ---- CSR build; one block per 128-row subrange; weight = val*inv_c*inv_r ----
__global__ __launch_bounds__(256)
void csr_build_kernel(const ull* __restrict__ br, const int* __restrict__ gfill_r,
                      const float* __restrict__ inv_c,
                      int* __restrict__ rowstart, int* __restrict__ rowend,
                      int2* __restrict__ cw, int N, int cap, int cap2) {
    __shared__ int cnt[SUBR];
    __shared__ float ds[SUBR];
    __shared__ int excl[SUBR];
    __shared__ int fill[SUBR];
    __shared__ float irs[SUBR];
    int q = blockIdx.x;
    int b = q >> 3, sub = q & 7;
    int t = threadIdx.x;
    if (t < SUBR) { cnt[t] = 0; ds[t] = 0.0f; fill[t] = 0; }
    __syncthreads();
    int s = b * cap, e = gfill_r[b * 16];
    int lo = sub * SUBR;
    // phase 1: filtered per-row count + weighted degree
    for (int i = s + t; i < e; i += 256) {
        ull p = br[i];
        int lr = (int)((p >> LRSHIFT) & LRMASK) - lo;
        if ((unsigned)lr < SUBR) {
            atomicAdd(&cnt[lr], 1);
            atomicAdd(&ds[lr], __uint_as_float((unsigned)(p >> 32)));
        }
    }
    __syncthreads();
    // phase 2: exclusive scan over 128
    if (t < SUBR) excl[t] = cnt[t];
    __syncthreads();
    for (int off = 1; off < SUBR; off <<= 1) {
        int v = 0;
        if (t < SUBR && t >= off) v = excl[t - off];
        __syncthreads();
        if (t < SUBR) excl[t] += v;
        __syncthreads();
    }
    int base2 = q * cap2;
    if (t < SUBR) {
        excl[t] -= cnt[t];
        int node = q * SUBR + t;
        if (node < N) {
            rowstart[node] = base2 + excl[t];
            rowend[node]   = base2 + excl[t] + cnt[t];
        }
        irs[t] = 1.0f / (sqrtf(ds[t]) + 1e-8f);
    }
    __syncthreads();
    // phase 3: filtered ranked placement with fully-folded weight
    for (int i = s + t; i < e; i += 256) {
        ull p = br[i];
        int lr = (int)((p >> LRSHIFT) & LRMASK) - lo;
        if ((unsigned)lr < SUBR) {
            int c = (int)(p & CMASK);
            float v = __uint_as_float((unsigned)(p >> 32));
            int pos = base2 + excl[lr] + atomicAdd(&fill[lr], 1);
            int2 packed;
            packed.x = c;
            packed.y = __float_as_int(v * inv_c[c] * irs[lr]);
            cw[pos] = packed;
        }
    }
}

// ---- fused: acc = nf (fp32), fb0 = bf16(nf) ----
__global__ void cvt_kernel(const float* __restrict__ src, float* __restrict__ acc,
                           unsigned int* __restrict__ dst, long n2) {
    long i = (long)blockIdx.x * blockDim.x + threadIdx.x;
    if (i < n2) {
        float2 v = ((const float2*)src)[i];
        ((float2*)acc)[i] = v;
        dst[i] = pack_bf16x2(v.x, v.y);
    }
}

// ---- SpMM: wave per row, lane = (edge-slot g, chunk h), bf16 gather ----
__global__ __launch_bounds__(256)
void spmm_bf16_kernel(const int* __restrict__ rowstart, const int* __restrict__ rowend,
                      const int2* __restrict__ cw,
                      const unsigned short* __restrict__ fin,
                      unsigned short* __restrict__ fout,
                      float* __restrict__ acc, int N) {
    int wid = blockIdx.x * (blockDim.x >> 6) + (threadIdx.x >> 6);   // row
    if (wid >= N) return;
    int lane = threadIdx.x & 63;
    int g = lane >> 3;          // edge slot 0..7
    int h = lane & 7;           // feature chunk (8 bf16 = 16 B)
    int s = rowstart[wid], e = rowend[wid];
    float a[8];
    #pragma unroll
    for (int k = 0; k < 8; k++) a[k] = 0.0f;
    for (int base = s; base < e; base += 8) {
        int j = base + g;
        int c = 0;
        float w = 0.0f;
        if (j < e) {
            int2 p = cw[j];
            c = p.x;
            w = __int_as_float(p.y);
        }
        uint4 q = ((const uint4*)(fin + ((long)c << 6)))[h];
        float f[8];
        f[0] = __uint_as_float(q.x << 16); f[1] = __uint_as_float(q.x & 0xffff0000u);
        f[2] = __uint_as_float(q.y << 16); f[3] = __uint_as_float(q.y & 0xffff0000u);
        f[4] = __uint_as_float(q.z << 16); f[5] = __uint_as_float(q.z & 0xffff0000u);
        f[6] = __uint_as_float(q.w << 16); f[7] = __uint_as_float(q.w & 0xffff0000u);
        #pragma unroll
        for (int k = 0; k < 8; k++) a[k] += w * f[k];
    }
    // reduce over the 8 edge slots (lane bits 3,4,5)
    #pragma unroll
    for (int k = 0; k < 8; k++) {
        a[k] += __shfl_xor(a[k], 8);
        a[k] += __shfl_xor(a[k], 16);
        a[k] += __shfl_xor(a[k], 32);
    }
    float ss = 0.0f;
    #pragma unroll
    for (int k = 0; k < 8; k++) ss += a[k] * a[k];
    ss += __shfl_xor(ss, 1);
    ss += __shfl_xor(ss, 2);
    ss += __shfl_xor(ss, 4);     // values g-replicated, h-reduction suffices
    float s2 = 1.0f / fmaxf(sqrtf(ss), 1e-12f);
    if (g == 0) {
        uint4 o;
        o.x = pack_bf16x2(a[0], a[1]);
        o.y = pack_bf16x2(a[2], a[3]);
        o.z = pack_bf16x2(a[4], a[5]);
        o.w = pack_bf16x2(a[6], a[7]);
        ((uint4*)(fout + ((long)wid << 6)))[h] = o;
        float4* ap = (float4*)(acc + ((long)wid << 6)) + (h << 1);
        float4 c0 = ap[0], c1 = ap[1];
        c0.x += a[0] * s2; c0.y += a[1] * s2; c0.z += a[2] * s2; c0.w += a[3] * s2;
        c1.x += a[4] * s2; c1.y += a[5] * s2; c1.z += a[6] * s2; c1.w += a[7] * s2;
        ap[0] = c0;
        ap[1] = c1;
    }
}

// ---- BPR loss ----
__global__ void loss_terms_kernel(const float* __restrict__ acc,
                                  const int* __restrict__ a_id, const int* __restrict__ p_id,
                                  const int* __restrict__ n_id,
                                  float* __restrict__ terms, int B) {
    long gid = (long)blockIdx.x * blockDim.x + threadIdx.x;
    int b = (int)(gid >> 6);
    int lane = threadIdx.x & 63;
    if (b < B) {
        int ia = a_id[b], ip = p_id[b], in2 = n_id[b];
        float a = acc[(long)ia * DDIM + lane];
        float p = acc[(long)ip * DDIM + lane];
        float n = acc[(long)in2 * DDIM + lane];
        float dp = a * p, dn = a * n;
        #pragma unroll
        for (int off = 1; off < 64; off <<= 1) { dp += __shfl_xor(dp, off); dn += __shfl_xor(dn, off); }
        if (lane == 0) {
            float x = (dp - dn) * 0.0625f;   // node_rep = acc/4 -> preds scale 1/16
            terms[b] = fmaxf(-x, 0.0f) + log1pf(expf(-fabsf(x)));
        }
    }
}

__global__ void reduce_kernel(const float* __restrict__ terms, float* __restrict__ out, int B) {
    __shared__ float sm[256];
    float s = 0.0f;
    for (int i = threadIdx.x; i < B; i += 256) s += terms[i];
    sm[threadIdx.x] = s;
    __syncthreads();
    for (int stride = 128; stride > 0; stride >>= 1) {
        if (threadIdx.x < stride) sm[threadIdx.x] += sm[threadIdx.x + stride];
        __syncthreads();
    }
    if (threadIdx.x == 0) out[0] = sm[0] / (float)B;
}

extern "C" void kernel_launch(void* const* d_in, const int* in_sizes, int n_in,
                              void* d_out, int out_size, void* d_ws, size_t ws_size,
                              hipStream_t stream) {
    const float* nf    = (const float*)d_in[0];
    const int*   erow  = (const int*)d_in[1];
    const int*   ecol  = (const int*)d_in[2];
    const float* evals = (const float*)d_in[3];
    const int*   a_id  = (const int*)d_in[4];
    const int*   p_id  = (const int*)d_in[5];
    const int*   n_id  = (const int*)d_in[6];

    int N = in_sizes[0] / DDIM;
    int E = in_sizes[1];
    int B = in_sizes[4];
    int NB = (N + BUCKET - 1) / BUCKET;
    int NQ = (N + SUBR - 1) / SUBR;
    int chunk = (E + NBLK - 1) / NBLK;

    // bucket capacity: mean + ~8.3% + 1024 (>14 sigma)
    long capl = ((long)E * BUCKET) / N;
    int cap = (int)(capl + capl / 12 + 1024);
    cap = (cap + 63) & ~63;
    // subrange capacity for cw: mean + 12.5% + 256 (>12 sigma)
    long m2 = ((long)E * SUBR) / N;
    int cap2 = (int)(m2 + m2 / 8 + 256);
    cap2 = (cap2 + 63) & ~63;

    size_t regionA = (size_t)cap * NB * 8;                 // br, later fb0+fb1
    size_t cwBytes = (size_t)cap2 * NQ * 8;
    size_t regionB = regionA > cwBytes ? regionA : cwBytes; // bc, later cw
    size_t featB32 = (size_t)N * DDIM * 4;
    size_t featB16 = (size_t)N * DDIM * 2;

    char* w = (char*)d_ws;
    ull*  br     = (ull*)w;
    char* regAp  = w;                 w += regionA;
    int2* bc     = (int2*)w;
    int2* cw     = (int2*)w;          w += regionB;
    float* acc   = (float*)w;         w += featB32;
    float* inv_c = (float*)w;         w += (size_t)N * 4;
    int* rowstart= (int*)w;           w += (size_t)N * 4;
    int* rowend  = (int*)w;           w += (size_t)N * 4;
    int* gfill_r = (int*)w;           w += (size_t)NB * 16 * 4;
    int* gfill_c = (int*)w;           w += (size_t)NB * 16 * 4;
    float* terms = (float*)w;         w += (size_t)B * 4;

    unsigned short* fb0 = (unsigned short*)regAp;             // aliases br (dead after csr_build)
    unsigned short* fb1 = (unsigned short*)(regAp + featB16);

    init_fill_kernel<<<1, 128, 0, stream>>>(gfill_r, gfill_c, NB, cap);
    binning_kernel<<<NBLK, TPB_BIN, 0, stream>>>(erow, ecol, evals, gfill_r, gfill_c,
                                                 br, bc, E, NB, chunk);
    degc_kernel<<<NQ, 256, 0, stream>>>(bc, gfill_c, inv_c, N, cap);
    csr_build_kernel<<<NQ, 256, 0, stream>>>(br, gfill_r, inv_c, rowstart, rowend, cw, N, cap, cap2);

    long n2 = (long)N * DDIM / 2;
    cvt_kernel<<<(unsigned)((n2 + 255) / 256), 256, 0, stream>>>(nf, acc, (unsigned int*)fb0, n2);

    unsigned spmmGrid = (unsigned)((N + 3) / 4);   // 4 waves (rows) per 256-thread block
    spmm_bf16_kernel<<<spmmGrid, 256, 0, stream>>>(rowstart, rowend, cw, fb0, fb1, acc, N);
    spmm_bf16_kernel<<<spmmGrid, 256, 0, stream>>>(rowstart, rowend, cw, fb1, fb0, acc, N);
    spmm_bf16_kernel<<<spmmGrid, 256, 0, stream>>>(rowstart, rowend, cw, fb0, fb1, acc, N);

    loss_terms_kernel<<<(unsigned)(((long)B * 64 + 255) / 256), 256, 0, stream>>>(
        acc, a_id, p_id, n_id, terms, B);
    reduce_kernel<<<1, 256, 0, stream>>>(terms, (float*)d_out, B);
}

// Round 8
// 523.318 us; speedup vs baseline: 1.1752x; 1.1752x over previous
//
#include <hip/hip_runtime.h>
#include <math.h>

#define DDIM 64
#define BUCKET 1024             // nodes per binning bucket
#define LRSHIFT 17              // packed: col [0,17), lrow [17,27), val [32,64)
#define CMASK 0x1FFFF
#define LRMASK 0x3FF
#define NBLK 512
#define TPB_BIN 512
#define MAXNB 128               // max buckets (NB = ceil(100000/1024) = 98)

typedef unsigned long long ull;

__device__ inline unsigned int pack_bf16x2(float lo, float hi) {
    unsigned int a = __float_as_uint(lo);
    unsigned int b = __float_as_uint(hi);
    a = (a + 0x7fffu + ((a >> 16) & 1u)) >> 16;          // RNE
    b = (b + 0x7fffu + ((b >> 16) & 1u)) & 0xffff0000u;  // RNE, keep high
    return a | b;
}

// ---- init global fill counters (cacheline-padded: stride 16 ints) ----
__global__ void init_fill_kernel(int* __restrict__ gfill_r, int* __restrict__ gfill_c,
                                 int NB, int cap) {
    int k = blockIdx.x * blockDim.x + threadIdx.x;
    if (k < NB) {
        gfill_r[k * 16] = k * cap;
        gfill_c[k * 16] = k * cap;
    }
}

// ---- fused binning with per-wave privatized histograms ----
__global__ __launch_bounds__(TPB_BIN)
void binning_kernel(const int* __restrict__ erow, const int* __restrict__ ecol,
                    const float* __restrict__ evals,
                    int* __restrict__ gfill_r, int* __restrict__ gfill_c,
                    ull* __restrict__ br, int2* __restrict__ bc,
                    int E, int NB, int chunk) {
    __shared__ int hr[8][MAXNB];
    __shared__ int hc[8][MAXNB];
    int t = threadIdx.x;
    int wv = t >> 6;
    for (int k = t; k < 8 * MAXNB; k += TPB_BIN) { (&hr[0][0])[k] = 0; (&hc[0][0])[k] = 0; }
    __syncthreads();
    int lo = blockIdx.x * chunk;
    int hi = min(E, lo + chunk);
    for (int i = lo + t; i < hi; i += TPB_BIN) {
        atomicAdd(&hr[wv][erow[i] >> 10], 1);
        atomicAdd(&hc[wv][ecol[i] >> 10], 1);
    }
    __syncthreads();
    if (t < NB) {
        int sr = 0, sc = 0;
        #pragma unroll
        for (int w2 = 0; w2 < 8; w2++) { sr += hr[w2][t]; sc += hc[w2][t]; }
        int basr = atomicAdd(&gfill_r[t * 16], sr);
        int basc = atomicAdd(&gfill_c[t * 16], sc);
        #pragma unroll
        for (int w2 = 0; w2 < 8; w2++) {
            int a = hr[w2][t]; hr[w2][t] = basr; basr += a;
            int b = hc[w2][t]; hc[w2][t] = basc; basc += b;
        }
    }
    __syncthreads();
    for (int i = lo + t; i < hi; i += TPB_BIN) {
        int r = erow[i];
        int c = ecol[i];
        float v = evals[i];
        int pos = atomicAdd(&hr[wv][r >> 10], 1);
        br[pos] = ((ull)__float_as_uint(v) << 32)
                | ((ull)(r & 1023) << LRSHIFT) | (unsigned)c;
        int pos2 = atomicAdd(&hc[wv][c >> 10], 1);
        int2 pc;
        pc.x = c & 1023;
        pc.y = __float_as_int(v);
        bc[pos2] = pc;
    }
}

// ---- count: block (bucket b, chunk ch) reads its 1/8 edge slice ONCE ----
__global__ __launch_bounds__(256)
void count_kernel(const ull* __restrict__ br, const int2* __restrict__ bc,
                  const int* __restrict__ gfill_r, const int* __restrict__ gfill_c,
                  int* __restrict__ subcnt, float* __restrict__ subds,
                  float* __restrict__ subdsc, int cap) {
    __shared__ int cnt[BUCKET];
    __shared__ float ds[BUCKET];
    __shared__ float dsc[BUCKET];
    int b = blockIdx.x >> 3, ch = blockIdx.x & 7;
    int t = threadIdx.x;
    for (int k = t; k < BUCKET; k += 256) { cnt[k] = 0; ds[k] = 0.0f; dsc[k] = 0.0f; }
    __syncthreads();
    int s = b * cap;
    // row-bucketed slice
    int e = gfill_r[b * 16];
    int len = ((e - s) + 7) >> 3;
    int cs = s + ch * len, ce = min(e, cs + len);
    for (int i = cs + t; i < ce; i += 256) {
        ull p = br[i];
        int lr = (int)((p >> LRSHIFT) & LRMASK);
        atomicAdd(&cnt[lr], 1);
        atomicAdd(&ds[lr], __uint_as_float((unsigned)(p >> 32)));
    }
    // col-bucketed slice
    int e2 = gfill_c[b * 16];
    int len2 = ((e2 - s) + 7) >> 3;
    int cs2 = s + ch * len2, ce2 = min(e2, cs2 + len2);
    for (int i = cs2 + t; i < ce2; i += 256) {
        int2 p = bc[i];
        atomicAdd(&dsc[p.x], __int_as_float(p.y));
    }
    __syncthreads();
    size_t base = ((size_t)b * 8 + ch) * BUCKET;
    for (int k = t; k < BUCKET; k += 256) {
        subcnt[base + k] = cnt[k];
        subds[base + k]  = ds[k];
        subdsc[base + k] = dsc[k];
    }
}

// ---- combine: per-bucket scan -> rowstart/rowend, per-chunk bases, inv_r, inv_c ----
__global__ __launch_bounds__(1024)
void combine_kernel(int* __restrict__ subcnt, const float* __restrict__ subds,
                    const float* __restrict__ subdsc,
                    int* __restrict__ rowstart, int* __restrict__ rowend,
                    float* __restrict__ inv_r, float* __restrict__ inv_c,
                    int N, int cap) {
    __shared__ int tot[BUCKET];
    int b = blockIdx.x, t = threadIdx.x;
    size_t base = (size_t)b * 8 * BUCKET;
    int c8[8];
    int sum = 0;
    #pragma unroll
    for (int c = 0; c < 8; c++) { c8[c] = subcnt[base + c * BUCKET + t]; sum += c8[c]; }
    tot[t] = sum;
    __syncthreads();
    for (int off = 1; off < BUCKET; off <<= 1) {
        int v = (t >= off) ? tot[t - off] : 0;
        __syncthreads();
        tot[t] += v;
        __syncthreads();
    }
    int excl = tot[t] - sum;
    int node = b * BUCKET + t;
    int s = b * cap;
    if (node < N) {
        rowstart[node] = s + excl;
        rowend[node]   = s + excl + sum;
    }
    int run = s + excl;
    #pragma unroll
    for (int c = 0; c < 8; c++) { int v = c8[c]; subcnt[base + c * BUCKET + t] = run; run += v; }
    float d = 0.0f, dc = 0.0f;
    #pragma unroll
    for (int c = 0; c < 8; c++) { d += subds[base + c * BUCKET + t]; dc += subdsc[base + c * BUCKET + t]; }
    inv_r[b * BUCKET + t] = 1.0f / (sqrtf(d) + 1e-8f);     // padded arrays: write always
    inv_c[b * BUCKET + t] = 1.0f / (sqrtf(dc) + 1e-8f);
}

// ---- place: block (b, ch) re-reads its slice, ranked placement, folded weight ----
__global__ __launch_bounds__(256)
void place_kernel(const ull* __restrict__ br, const int* __restrict__ gfill_r,
                  const int* __restrict__ pbase, const float* __restrict__ inv_r,
                  const float* __restrict__ inv_c,
                  int2* __restrict__ cw, int cap) {
    __shared__ int fill[BUCKET];
    __shared__ float irs[BUCKET];
    int b = blockIdx.x >> 3, ch = blockIdx.x & 7;
    int t = threadIdx.x;
    size_t pb = ((size_t)b * 8 + ch) * BUCKET;
    for (int k = t; k < BUCKET; k += 256) {
        fill[k] = pbase[pb + k];
        irs[k]  = inv_r[b * BUCKET + k];
    }
    __syncthreads();
    int s = b * cap;
    int e = gfill_r[b * 16];
    int len = ((e - s) + 7) >> 3;
    int cs = s + ch * len, ce = min(e, cs + len);
    for (int i = cs + t; i < ce; i += 256) {
        ull p = br[i];
        int c = (int)(p & CMASK);
        int lr = (int)((p >> LRSHIFT) & LRMASK);
        float v = __uint_as_float((unsigned)(p >> 32));
        int pos = atomicAdd(&fill[lr], 1);
        int2 pk;
        pk.x = c;
        pk.y = __float_as_int(v * inv_c[c] * irs[lr]);
        cw[pos] = pk;
    }
}

// ---- fused: acc = nf (fp32), fb0 = bf16(nf) ----
__global__ void cvt_kernel(const float* __restrict__ src, float* __restrict__ acc,
                           unsigned int* __restrict__ dst, long n2) {
    long i = (long)blockIdx.x * blockDim.x + threadIdx.x;
    if (i < n2) {
        float2 v = ((const float2*)src)[i];
        ((float2*)acc)[i] = v;
        dst[i] = pack_bf16x2(v.x, v.y);
    }
}

// ---- SpMM: wave per row, lane = (edge-slot g, chunk h), bf16 gather ----
__global__ __launch_bounds__(256)
void spmm_bf16_kernel(const int* __restrict__ rowstart, const int* __restrict__ rowend,
                      const int2* __restrict__ cw,
                      const unsigned short* __restrict__ fin,
                      unsigned short* __restrict__ fout,
                      float* __restrict__ acc, int N) {
    int wid = blockIdx.x * (blockDim.x >> 6) + (threadIdx.x >> 6);   // row
    if (wid >= N) return;
    int lane = threadIdx.x & 63;
    int g = lane >> 3;          // edge slot 0..7
    int h = lane & 7;           // feature chunk (8 bf16 = 16 B)
    int s = rowstart[wid], e = rowend[wid];
    float a[8];
    #pragma unroll
    for (int k = 0; k < 8; k++) a[k] = 0.0f;
    for (int base = s; base < e; base += 8) {
        int j = base + g;
        int c = 0;
        float w = 0.0f;
        if (j < e) {
            int2 p = cw[j];
            c = p.x;
            w = __int_as_float(p.y);
        }
        uint4 q = ((const uint4*)(fin + ((long)c << 6)))[h];
        float f[8];
        f[0] = __uint_as_float(q.x << 16); f[1] = __uint_as_float(q.x & 0xffff0000u);
        f[2] = __uint_as_float(q.y << 16); f[3] = __uint_as_float(q.y & 0xffff0000u);
        f[4] = __uint_as_float(q.z << 16); f[5] = __uint_as_float(q.z & 0xffff0000u);
        f[6] = __uint_as_float(q.w << 16); f[7] = __uint_as_float(q.w & 0xffff0000u);
        #pragma unroll
        for (int k = 0; k < 8; k++) a[k] += w * f[k];
    }
    #pragma unroll
    for (int k = 0; k < 8; k++) {
        a[k] += __shfl_xor(a[k], 8);
        a[k] += __shfl_xor(a[k], 16);
        a[k] += __shfl_xor(a[k], 32);
    }
    float ss = 0.0f;
    #pragma unroll
    for (int k = 0; k < 8; k++) ss += a[k] * a[k];
    ss += __shfl_xor(ss, 1);
    ss += __shfl_xor(ss, 2);
    ss += __shfl_xor(ss, 4);
    float s2 = 1.0f / fmaxf(sqrtf(ss), 1e-12f);
    if (g == 0) {
        uint4 o;
        o.x = pack_bf16x2(a[0], a[1]);
        o.y = pack_bf16x2(a[2], a[3]);
        o.z = pack_bf16x2(a[4], a[5]);
        o.w = pack_bf16x2(a[6], a[7]);
        ((uint4*)(fout + ((long)wid << 6)))[h] = o;
        float4* ap = (float4*)(acc + ((long)wid << 6)) + (h << 1);
        float4 c0 = ap[0], c1 = ap[1];
        c0.x += a[0] * s2; c0.y += a[1] * s2; c0.z += a[2] * s2; c0.w += a[3] * s2;
        c1.x += a[4] * s2; c1.y += a[5] * s2; c1.z += a[6] * s2; c1.w += a[7] * s2;
        ap[0] = c0;
        ap[1] = c1;
    }
}

// ---- BPR loss ----
__global__ void loss_terms_kernel(const float* __restrict__ acc,
                                  const int* __restrict__ a_id, const int* __restrict__ p_id,
                                  const int* __restrict__ n_id,
                                  float* __restrict__ terms, int B) {
    long gid = (long)blockIdx.x * blockDim.x + threadIdx.x;
    int b = (int)(gid >> 6);
    int lane = threadIdx.x & 63;
    if (b < B) {
        int ia = a_id[b], ip = p_id[b], in2 = n_id[b];
        float a = acc[(long)ia * DDIM + lane];
        float p = acc[(long)ip * DDIM + lane];
        float n = acc[(long)in2 * DDIM + lane];
        float dp = a * p, dn = a * n;
        #pragma unroll
        for (int off = 1; off < 64; off <<= 1) { dp += __shfl_xor(dp, off); dn += __shfl_xor(dn, off); }
        if (lane == 0) {
            float x = (dp - dn) * 0.0625f;   // node_rep = acc/4 -> preds scale 1/16
            terms[b] = fmaxf(-x, 0.0f) + log1pf(expf(-fabsf(x)));
        }
    }
}

__global__ void reduce_kernel(const float* __restrict__ terms, float* __restrict__ out, int B) {
    __shared__ float sm[256];
    float s = 0.0f;
    for (int i = threadIdx.x; i < B; i += 256) s += terms[i];
    sm[threadIdx.x] = s;
    __syncthreads();
    for (int stride = 128; stride > 0; stride >>= 1) {
        if (threadIdx.x < stride) sm[threadIdx.x] += sm[threadIdx.x + stride];
        __syncthreads();
    }
    if (threadIdx.x == 0) out[0] = sm[0] / (float)B;
}

extern "C" void kernel_launch(void* const* d_in, const int* in_sizes, int n_in,
                              void* d_out, int out_size, void* d_ws, size_t ws_size,
                              hipStream_t stream) {
    const float* nf    = (const float*)d_in[0];
    const int*   erow  = (const int*)d_in[1];
    const int*   ecol  = (const int*)d_in[2];
    const float* evals = (const float*)d_in[3];
    const int*   a_id  = (const int*)d_in[4];
    const int*   p_id  = (const int*)d_in[5];
    const int*   n_id  = (const int*)d_in[6];

    int N = in_sizes[0] / DDIM;
    int E = in_sizes[1];
    int B = in_sizes[4];
    int NB = (N + BUCKET - 1) / BUCKET;
    int chunk = (E + NBLK - 1) / NBLK;
    int Npad = NB * BUCKET;

    // bucket capacity: mean + ~8.3% + 1024 (>14 sigma)
    long capl = ((long)E * BUCKET) / N;
    int cap = (int)(capl + capl / 12 + 1024);
    cap = (cap + 63) & ~63;

    size_t regionBytes = (size_t)cap * NB * 8;
    size_t featB32 = (size_t)N * DDIM * 4;
    size_t featB16 = (size_t)N * DDIM * 2;
    size_t subBytes = (size_t)NB * 8 * BUCKET * 4;

    char* w = (char*)d_ws;
    ull*  br     = (ull*)w;           // region A: later fb0+fb1
    char* regAp  = w;                 w += regionBytes;
    int2* bc     = (int2*)w;          // region B: later cw
    int2* cw     = (int2*)w;          w += regionBytes;
    float* acc   = (float*)w;         w += featB32;
    int* subcnt  = (int*)w;           w += subBytes;    // becomes pbase in combine
    float* subds = (float*)w;         w += subBytes;
    float* subdsc= (float*)w;         w += subBytes;
    float* inv_c = (float*)w;         w += (size_t)Npad * 4;
    float* inv_r = (float*)w;         w += (size_t)Npad * 4;
    int* rowstart= (int*)w;           w += (size_t)N * 4;
    int* rowend  = (int*)w;           w += (size_t)N * 4;
    int* gfill_r = (int*)w;           w += (size_t)NB * 16 * 4;
    int* gfill_c = (int*)w;           w += (size_t)NB * 16 * 4;
    float* terms = (float*)w;         w += (size_t)B * 4;

    unsigned short* fb0 = (unsigned short*)regAp;             // aliases br (dead after place)
    unsigned short* fb1 = (unsigned short*)(regAp + featB16);

    init_fill_kernel<<<1, 128, 0, stream>>>(gfill_r, gfill_c, NB, cap);
    binning_kernel<<<NBLK, TPB_BIN, 0, stream>>>(erow, ecol, evals, gfill_r, gfill_c,
                                                 br, bc, E, NB, chunk);
    count_kernel<<<NB * 8, 256, 0, stream>>>(br, bc, gfill_r, gfill_c,
                                             subcnt, subds, subdsc, cap);
    combine_kernel<<<NB, 1024, 0, stream>>>(subcnt, subds, subdsc, rowstart, rowend,
                                            inv_r, inv_c, N, cap);
    place_kernel<<<NB * 8, 256, 0, stream>>>(br, gfill_r, subcnt, inv_r, inv_c, cw, cap);

    long n2 = (long)N * DDIM / 2;
    cvt_kernel<<<(unsigned)((n2 + 255) / 256), 256, 0, stream>>>(nf, acc, (unsigned int*)fb0, n2);

    unsigned spmmGrid = (unsigned)((N + 3) / 4);   // 4 waves (rows) per 256-thread block
    spmm_bf16_kernel<<<spmmGrid, 256, 0, stream>>>(rowstart, rowend, cw, fb0, fb1, acc, N);
    spmm_bf16_kernel<<<spmmGrid, 256, 0, stream>>>(rowstart, rowend, cw, fb1, fb0, acc, N);
    spmm_bf16_kernel<<<spmmGrid, 256, 0, stream>>>(rowstart, rowend, cw, fb0, fb1, acc, N);

    loss_terms_kernel<<<(unsigned)(((long)B * 64 + 255) / 256), 256, 0, stream>>>(
        acc, a_id, p_id, n_id, terms, B);
    reduce_kernel<<<1, 256, 0, stream>>>(terms, (float*)d_out, B);
}

// Round 9
// 495.312 us; speedup vs baseline: 1.2417x; 1.0565x over previous
//
#include <hip/hip_runtime.h>
#include <math.h>

#define DDIM 64
#define BUCKET 1024             // nodes per binning bucket
#define LRSHIFT 17              // packed: col [0,17), lrow [17,27), val [32,64)
#define CMASK 0x1FFFF
#define LRMASK 0x3FF
#define NBLK 512
#define TPB_BIN 512
#define MAXNB 128               // max buckets (NB = ceil(100000/1024) = 98)

typedef unsigned long long ull;

__device__ inline unsigned int pack_bf16x2(float lo, float hi) {
    unsigned int a = __float_as_uint(lo);
    unsigned int b = __float_as_uint(hi);
    a = (a + 0x7fffu + ((a >> 16) & 1u)) >> 16;          // RNE
    b = (b + 0x7fffu + ((b >> 16) & 1u)) & 0xffff0000u;  // RNE, keep high
    return a | b;
}

__device__ inline unsigned int bf16_hi(float v) {       // RNE bf16 bits in high 16
    unsigned int a = __float_as_uint(v);
    return (a + 0x7fffu + ((a >> 16) & 1u)) & 0xffff0000u;
}

// ---- init global fill counters (cacheline-padded: stride 16 ints) ----
__global__ void init_fill_kernel(int* __restrict__ gfill_r, int* __restrict__ gfill_c,
                                 int NB, int cap) {
    int k = blockIdx.x * blockDim.x + threadIdx.x;
    if (k < NB) {
        gfill_r[k * 16] = k * cap;
        gfill_c[k * 16] = k * cap;
    }
}

// ---- fused binning: per-wave count, BLOCK-level reserve + place ----
__global__ __launch_bounds__(TPB_BIN)
void binning_kernel(const int* __restrict__ erow, const int* __restrict__ ecol,
                    const float* __restrict__ evals,
                    int* __restrict__ gfill_r, int* __restrict__ gfill_c,
                    ull* __restrict__ br, unsigned int* __restrict__ bc,
                    int E, int NB, int chunk) {
    __shared__ int hr[8][MAXNB];
    __shared__ int hc[8][MAXNB];
    __shared__ int fr[MAXNB];     // block-level fill cursors (row key)
    __shared__ int fc[MAXNB];     // block-level fill cursors (col key)
    int t = threadIdx.x;
    int wv = t >> 6;
    for (int k = t; k < 8 * MAXNB; k += TPB_BIN) { (&hr[0][0])[k] = 0; (&hc[0][0])[k] = 0; }
    __syncthreads();
    int lo = blockIdx.x * chunk;
    int hi = min(E, lo + chunk);
    // phase 1: per-wave count (contention relief only)
    for (int i = lo + t; i < hi; i += TPB_BIN) {
        atomicAdd(&hr[wv][erow[i] >> 10], 1);
        atomicAdd(&hc[wv][ecol[i] >> 10], 1);
    }
    __syncthreads();
    // phase 2: ONE reservation per (block,bucket) -> long contiguous output runs
    if (t < NB) {
        int sr = 0, sc = 0;
        #pragma unroll
        for (int w2 = 0; w2 < 8; w2++) { sr += hr[w2][t]; sc += hc[w2][t]; }
        fr[t] = atomicAdd(&gfill_r[t * 16], sr);
        fc[t] = atomicAdd(&gfill_c[t * 16], sc);
    }
    __syncthreads();
    // phase 3: place with block-shared cursors (runs ~64 edges, 512 B)
    for (int i = lo + t; i < hi; i += TPB_BIN) {
        int r = erow[i];
        int c = ecol[i];
        float v = evals[i];
        int pos = atomicAdd(&fr[r >> 10], 1);
        br[pos] = ((ull)__float_as_uint(v) << 32)
                | ((ull)(r & 1023) << LRSHIFT) | (unsigned)c;
        int pos2 = atomicAdd(&fc[c >> 10], 1);
        bc[pos2] = bf16_hi(v) | (unsigned)(c & 1023);   // 4 B packed
    }
}

// ---- count: block (bucket b, chunk ch) reads its 1/8 edge slice ONCE ----
__global__ __launch_bounds__(256)
void count_kernel(const ull* __restrict__ br, const unsigned int* __restrict__ bc,
                  const int* __restrict__ gfill_r, const int* __restrict__ gfill_c,
                  int* __restrict__ subcnt, float* __restrict__ subds,
                  float* __restrict__ subdsc, int cap) {
    __shared__ int cnt[BUCKET];
    __shared__ float ds[BUCKET];
    __shared__ float dsc[BUCKET];
    int b = blockIdx.x >> 3, ch = blockIdx.x & 7;
    int t = threadIdx.x;
    for (int k = t; k < BUCKET; k += 256) { cnt[k] = 0; ds[k] = 0.0f; dsc[k] = 0.0f; }
    __syncthreads();
    int s = b * cap;
    // row-bucketed slice
    int e = gfill_r[b * 16];
    int len = ((e - s) + 7) >> 3;
    int cs = s + ch * len, ce = min(e, cs + len);
    for (int i = cs + t; i < ce; i += 256) {
        ull p = br[i];
        int lr = (int)((p >> LRSHIFT) & LRMASK);
        atomicAdd(&cnt[lr], 1);
        atomicAdd(&ds[lr], __uint_as_float((unsigned)(p >> 32)));
    }
    // col-bucketed slice (packed 4 B)
    int e2 = gfill_c[b * 16];
    int len2 = ((e2 - s) + 7) >> 3;
    int cs2 = s + ch * len2, ce2 = min(e2, cs2 + len2);
    for (int i = cs2 + t; i < ce2; i += 256) {
        unsigned int p = bc[i];
        atomicAdd(&dsc[p & 0x3FFu], __uint_as_float(p & 0xffff0000u));
    }
    __syncthreads();
    size_t base = ((size_t)b * 8 + ch) * BUCKET;
    for (int k = t; k < BUCKET; k += 256) {
        subcnt[base + k] = cnt[k];
        subds[base + k]  = ds[k];
        subdsc[base + k] = dsc[k];
    }
}

// ---- combine: per-bucket scan -> rowstart/rowend, per-chunk bases, inv_r, inv_c ----
__global__ __launch_bounds__(1024)
void combine_kernel(int* __restrict__ subcnt, const float* __restrict__ subds,
                    const float* __restrict__ subdsc,
                    int* __restrict__ rowstart, int* __restrict__ rowend,
                    float* __restrict__ inv_r, float* __restrict__ inv_c,
                    int N, int cap) {
    __shared__ int tot[BUCKET];
    int b = blockIdx.x, t = threadIdx.x;
    size_t base = (size_t)b * 8 * BUCKET;
    int c8[8];
    int sum = 0;
    #pragma unroll
    for (int c = 0; c < 8; c++) { c8[c] = subcnt[base + c * BUCKET + t]; sum += c8[c]; }
    tot[t] = sum;
    __syncthreads();
    for (int off = 1; off < BUCKET; off <<= 1) {
        int v = (t >= off) ? tot[t - off] : 0;
        __syncthreads();
        tot[t] += v;
        __syncthreads();
    }
    int excl = tot[t] - sum;
    int node = b * BUCKET + t;
    int s = b * cap;
    if (node < N) {
        rowstart[node] = s + excl;
        rowend[node]   = s + excl + sum;
    }
    int run = s + excl;
    #pragma unroll
    for (int c = 0; c < 8; c++) { int v = c8[c]; subcnt[base + c * BUCKET + t] = run; run += v; }
    float d = 0.0f, dc = 0.0f;
    #pragma unroll
    for (int c = 0; c < 8; c++) { d += subds[base + c * BUCKET + t]; dc += subdsc[base + c * BUCKET + t]; }
    inv_r[b * BUCKET + t] = 1.0f / (sqrtf(d) + 1e-8f);     // padded arrays: write always
    inv_c[b * BUCKET + t] = 1.0f / (sqrtf(dc) + 1e-8f);
}

// ---- place: block (b, ch) re-reads its slice, ranked placement, folded weight ----
__global__ __launch_bounds__(256)
void place_kernel(const ull* __restrict__ br, const int* __restrict__ gfill_r,
                  const int* __restrict__ pbase, const float* __restrict__ inv_r,
                  const float* __restrict__ inv_c,
                  int2* __restrict__ cw, int cap) {
    __shared__ int fill[BUCKET];
    __shared__ float irs[BUCKET];
    int b = blockIdx.x >> 3, ch = blockIdx.x & 7;
    int t = threadIdx.x;
    size_t pb = ((size_t)b * 8 + ch) * BUCKET;
    for (int k = t; k < BUCKET; k += 256) {
        fill[k] = pbase[pb + k];
        irs[k]  = inv_r[b * BUCKET + k];
    }
    __syncthreads();
    int s = b * cap;
    int e = gfill_r[b * 16];
    int len = ((e - s) + 7) >> 3;
    int cs = s + ch * len, ce = min(e, cs + len);
    for (int i = cs + t; i < ce; i += 256) {
        ull p = br[i];
        int c = (int)(p & CMASK);
        int lr = (int)((p >> LRSHIFT) & LRMASK);
        float v = __uint_as_float((unsigned)(p >> 32));
        int pos = atomicAdd(&fill[lr], 1);
        int2 pk;
        pk.x = c;
        pk.y = __float_as_int(v * inv_c[c] * irs[lr]);
        cw[pos] = pk;
    }
}

// ---- fused: acc = nf (fp32), fb0 = bf16(nf) ----
__global__ void cvt_kernel(const float* __restrict__ src, float* __restrict__ acc,
                           unsigned int* __restrict__ dst, long n2) {
    long i = (long)blockIdx.x * blockDim.x + threadIdx.x;
    if (i < n2) {
        float2 v = ((const float2*)src)[i];
        ((float2*)acc)[i] = v;
        dst[i] = pack_bf16x2(v.x, v.y);
    }
}

// ---- SpMM: wave per row, lane = (edge-slot g, chunk h), bf16 gather ----
__global__ __launch_bounds__(256)
void spmm_bf16_kernel(const int* __restrict__ rowstart, const int* __restrict__ rowend,
                      const int2* __restrict__ cw,
                      const unsigned short* __restrict__ fin,
                      unsigned short* __restrict__ fout,
                      float* __restrict__ acc, int N) {
    int wid = blockIdx.x * (blockDim.x >> 6) + (threadIdx.x >> 6);   // row
    if (wid >= N) return;
    int lane = threadIdx.x & 63;
    int g = lane >> 3;          // edge slot 0..7
    int h = lane & 7;           // feature chunk (8 bf16 = 16 B)
    int s = rowstart[wid], e = rowend[wid];
    float a[8];
    #pragma unroll
    for (int k = 0; k < 8; k++) a[k] = 0.0f;
    for (int base = s; base < e; base += 8) {
        int j = base + g;
        int c = 0;
        float w = 0.0f;
        if (j < e) {
            int2 p = cw[j];
            c = p.x;
            w = __int_as_float(p.y);
        }
        uint4 q = ((const uint4*)(fin + ((long)c << 6)))[h];
        float f[8];
        f[0] = __uint_as_float(q.x << 16); f[1] = __uint_as_float(q.x & 0xffff0000u);
        f[2] = __uint_as_float(q.y << 16); f[3] = __uint_as_float(q.y & 0xffff0000u);
        f[4] = __uint_as_float(q.z << 16); f[5] = __uint_as_float(q.z & 0xffff0000u);
        f[6] = __uint_as_float(q.w << 16); f[7] = __uint_as_float(q.w & 0xffff0000u);
        #pragma unroll
        for (int k = 0; k < 8; k++) a[k] += w * f[k];
    }
    #pragma unroll
    for (int k = 0; k < 8; k++) {
        a[k] += __shfl_xor(a[k], 8);
        a[k] += __shfl_xor(a[k], 16);
        a[k] += __shfl_xor(a[k], 32);
    }
    float ss = 0.0f;
    #pragma unroll
    for (int k = 0; k < 8; k++) ss += a[k] * a[k];
    ss += __shfl_xor(ss, 1);
    ss += __shfl_xor(ss, 2);
    ss += __shfl_xor(ss, 4);
    float s2 = 1.0f / fmaxf(sqrtf(ss), 1e-12f);
    if (g == 0) {
        uint4 o;
        o.x = pack_bf16x2(a[0], a[1]);
        o.y = pack_bf16x2(a[2], a[3]);
        o.z = pack_bf16x2(a[4], a[5]);
        o.w = pack_bf16x2(a[6], a[7]);
        ((uint4*)(fout + ((long)wid << 6)))[h] = o;
        float4* ap = (float4*)(acc + ((long)wid << 6)) + (h << 1);
        float4 c0 = ap[0], c1 = ap[1];
        c0.x += a[0] * s2; c0.y += a[1] * s2; c0.z += a[2] * s2; c0.w += a[3] * s2;
        c1.x += a[4] * s2; c1.y += a[5] * s2; c1.z += a[6] * s2; c1.w += a[7] * s2;
        ap[0] = c0;
        ap[1] = c1;
    }
}

// ---- BPR loss ----
__global__ void loss_terms_kernel(const float* __restrict__ acc,
                                  const int* __restrict__ a_id, const int* __restrict__ p_id,
                                  const int* __restrict__ n_id,
                                  float* __restrict__ terms, int B) {
    long gid = (long)blockIdx.x * blockDim.x + threadIdx.x;
    int b = (int)(gid >> 6);
    int lane = threadIdx.x & 63;
    if (b < B) {
        int ia = a_id[b], ip = p_id[b], in2 = n_id[b];
        float a = acc[(long)ia * DDIM + lane];
        float p = acc[(long)ip * DDIM + lane];
        float n = acc[(long)in2 * DDIM + lane];
        float dp = a * p, dn = a * n;
        #pragma unroll
        for (int off = 1; off < 64; off <<= 1) { dp += __shfl_xor(dp, off); dn += __shfl_xor(dn, off); }
        if (lane == 0) {
            float x = (dp - dn) * 0.0625f;   // node_rep = acc/4 -> preds scale 1/16
            terms[b] = fmaxf(-x, 0.0f) + log1pf(expf(-fabsf(x)));
        }
    }
}

__global__ void reduce_kernel(const float* __restrict__ terms, float* __restrict__ out, int B) {
    __shared__ float sm[256];
    float s = 0.0f;
    for (int i = threadIdx.x; i < B; i += 256) s += terms[i];
    sm[threadIdx.x] = s;
    __syncthreads();
    for (int stride = 128; stride > 0; stride >>= 1) {
        if (threadIdx.x < stride) sm[threadIdx.x] += sm[threadIdx.x + stride];
        __syncthreads();
    }
    if (threadIdx.x == 0) out[0] = sm[0] / (float)B;
}

extern "C" void kernel_launch(void* const* d_in, const int* in_sizes, int n_in,
                              void* d_out, int out_size, void* d_ws, size_t ws_size,
                              hipStream_t stream) {
    const float* nf    = (const float*)d_in[0];
    const int*   erow  = (const int*)d_in[1];
    const int*   ecol  = (const int*)d_in[2];
    const float* evals = (const float*)d_in[3];
    const int*   a_id  = (const int*)d_in[4];
    const int*   p_id  = (const int*)d_in[5];
    const int*   n_id  = (const int*)d_in[6];

    int N = in_sizes[0] / DDIM;
    int E = in_sizes[1];
    int B = in_sizes[4];
    int NB = (N + BUCKET - 1) / BUCKET;
    int chunk = (E + NBLK - 1) / NBLK;
    int Npad = NB * BUCKET;

    // bucket capacity: mean + ~8.3% + 1024 (>14 sigma)
    long capl = ((long)E * BUCKET) / N;
    int cap = (int)(capl + capl / 12 + 1024);
    cap = (cap + 63) & ~63;

    size_t regionBytes = (size_t)cap * NB * 8;
    size_t featB32 = (size_t)N * DDIM * 4;
    size_t featB16 = (size_t)N * DDIM * 2;
    size_t subBytes = (size_t)NB * 8 * BUCKET * 4;

    char* w = (char*)d_ws;
    ull*  br     = (ull*)w;           // region A: later fb0+fb1
    char* regAp  = w;                 w += regionBytes;
    unsigned int* bc = (unsigned int*)w;  // region B: bc (4 B/entry), later cw (8 B/entry)
    int2* cw     = (int2*)w;          w += regionBytes;
    float* acc   = (float*)w;         w += featB32;
    int* subcnt  = (int*)w;           w += subBytes;    // becomes pbase in combine
    float* subds = (float*)w;         w += subBytes;
    float* subdsc= (float*)w;         w += subBytes;
    float* inv_c = (float*)w;         w += (size_t)Npad * 4;
    float* inv_r = (float*)w;         w += (size_t)Npad * 4;
    int* rowstart= (int*)w;           w += (size_t)N * 4;
    int* rowend  = (int*)w;           w += (size_t)N * 4;
    int* gfill_r = (int*)w;           w += (size_t)NB * 16 * 4;
    int* gfill_c = (int*)w;           w += (size_t)NB * 16 * 4;
    float* terms = (float*)w;         w += (size_t)B * 4;

    unsigned short* fb0 = (unsigned short*)regAp;             // aliases br (dead after place)
    unsigned short* fb1 = (unsigned short*)(regAp + featB16);

    init_fill_kernel<<<1, 128, 0, stream>>>(gfill_r, gfill_c, NB, cap);
    binning_kernel<<<NBLK, TPB_BIN, 0, stream>>>(erow, ecol, evals, gfill_r, gfill_c,
                                                 br, bc, E, NB, chunk);
    count_kernel<<<NB * 8, 256, 0, stream>>>(br, bc, gfill_r, gfill_c,
                                             subcnt, subds, subdsc, cap);
    combine_kernel<<<NB, 1024, 0, stream>>>(subcnt, subds, subdsc, rowstart, rowend,
                                            inv_r, inv_c, N, cap);
    place_kernel<<<NB * 8, 256, 0, stream>>>(br, gfill_r, subcnt, inv_r, inv_c, cw, cap);

    long n2 = (long)N * DDIM / 2;
    cvt_kernel<<<(unsigned)((n2 + 255) / 256), 256, 0, stream>>>(nf, acc, (unsigned int*)fb0, n2);

    unsigned spmmGrid = (unsigned)((N + 3) / 4);   // 4 waves (rows) per 256-thread block
    spmm_bf16_kernel<<<spmmGrid, 256, 0, stream>>>(rowstart, rowend, cw, fb0, fb1, acc, N);
    spmm_bf16_kernel<<<spmmGrid, 256, 0, stream>>>(rowstart, rowend, cw, fb1, fb0, acc, N);
    spmm_bf16_kernel<<<spmmGrid, 256, 0, stream>>>(rowstart, rowend, cw, fb0, fb1, acc, N);

    loss_terms_kernel<<<(unsigned)(((long)B * 64 + 255) / 256), 256, 0, stream>>>(
        acc, a_id, p_id, n_id, terms, B);
    reduce_kernel<<<1, 256, 0, stream>>>(terms, (float*)d_out, B);
}

// Round 10
// 454.340 us; speedup vs baseline: 1.3536x; 1.0902x over previous
//
#include <hip/hip_runtime.h>
#include <math.h>

#define DDIM 64
#define BUCKET 1024             // nodes per binning bucket
#define LRSHIFT 17              // packed: col [0,17), lrow [17,27), val [32,64)
#define CMASK 0x1FFFF
#define LRMASK 0x3FF
#define NBLK 512
#define TPB_BIN 512
#define MAXNB 128               // max buckets (NB = ceil(100000/1024) = 98)

typedef unsigned long long ull;
typedef _Float16 half2_t __attribute__((ext_vector_type(2)));

__device__ inline unsigned int bf16_hi(float v) {       // RNE bf16 bits in high 16
    unsigned int a = __float_as_uint(v);
    return (a + 0x7fffu + ((a >> 16) & 1u)) & 0xffff0000u;
}

__device__ inline unsigned int pk_f16x2(float lo, float hi) {
    return __builtin_bit_cast(unsigned int, __builtin_amdgcn_cvt_pkrtz(lo, hi));
}

// ---- init global fill counters (cacheline-padded: stride 16 ints) ----
__global__ void init_fill_kernel(int* __restrict__ gfill_r, int* __restrict__ gfill_c,
                                 int NB, int cap) {
    int k = blockIdx.x * blockDim.x + threadIdx.x;
    if (k < NB) {
        gfill_r[k * 16] = k * cap;
        gfill_c[k * 16] = k * cap;
    }
}

// ---- fused binning: per-wave count, BLOCK-level reserve + place ----
__global__ __launch_bounds__(TPB_BIN)
void binning_kernel(const int* __restrict__ erow, const int* __restrict__ ecol,
                    const float* __restrict__ evals,
                    int* __restrict__ gfill_r, int* __restrict__ gfill_c,
                    ull* __restrict__ br, unsigned int* __restrict__ bc,
                    int E, int NB, int chunk) {
    __shared__ int hr[8][MAXNB];
    __shared__ int hc[8][MAXNB];
    __shared__ int fr[MAXNB];
    __shared__ int fc[MAXNB];
    int t = threadIdx.x;
    int wv = t >> 6;
    for (int k = t; k < 8 * MAXNB; k += TPB_BIN) { (&hr[0][0])[k] = 0; (&hc[0][0])[k] = 0; }
    __syncthreads();
    int lo = blockIdx.x * chunk;
    int hi = min(E, lo + chunk);
    for (int i = lo + t; i < hi; i += TPB_BIN) {
        atomicAdd(&hr[wv][erow[i] >> 10], 1);
        atomicAdd(&hc[wv][ecol[i] >> 10], 1);
    }
    __syncthreads();
    if (t < NB) {
        int sr = 0, sc = 0;
        #pragma unroll
        for (int w2 = 0; w2 < 8; w2++) { sr += hr[w2][t]; sc += hc[w2][t]; }
        fr[t] = atomicAdd(&gfill_r[t * 16], sr);
        fc[t] = atomicAdd(&gfill_c[t * 16], sc);
    }
    __syncthreads();
    for (int i = lo + t; i < hi; i += TPB_BIN) {
        int r = erow[i];
        int c = ecol[i];
        float v = evals[i];
        int pos = atomicAdd(&fr[r >> 10], 1);
        br[pos] = ((ull)__float_as_uint(v) << 32)
                | ((ull)(r & 1023) << LRSHIFT) | (unsigned)c;
        int pos2 = atomicAdd(&fc[c >> 10], 1);
        bc[pos2] = bf16_hi(v) | (unsigned)(c & 1023);   // 4 B packed
    }
}

// ---- count: block (bucket b, chunk ch) reads its 1/8 edge slice ONCE ----
__global__ __launch_bounds__(256)
void count_kernel(const ull* __restrict__ br, const unsigned int* __restrict__ bc,
                  const int* __restrict__ gfill_r, const int* __restrict__ gfill_c,
                  int* __restrict__ subcnt, float* __restrict__ subds,
                  float* __restrict__ subdsc, int cap) {
    __shared__ int cnt[BUCKET];
    __shared__ float ds[BUCKET];
    __shared__ float dsc[BUCKET];
    int b = blockIdx.x >> 3, ch = blockIdx.x & 7;
    int t = threadIdx.x;
    for (int k = t; k < BUCKET; k += 256) { cnt[k] = 0; ds[k] = 0.0f; dsc[k] = 0.0f; }
    __syncthreads();
    int s = b * cap;
    int e = gfill_r[b * 16];
    int len = ((e - s) + 7) >> 3;
    int cs = s + ch * len, ce = min(e, cs + len);
    for (int i = cs + t; i < ce; i += 256) {
        ull p = br[i];
        int lr = (int)((p >> LRSHIFT) & LRMASK);
        atomicAdd(&cnt[lr], 1);
        atomicAdd(&ds[lr], __uint_as_float((unsigned)(p >> 32)));
    }
    int e2 = gfill_c[b * 16];
    int len2 = ((e2 - s) + 7) >> 3;
    int cs2 = s + ch * len2, ce2 = min(e2, cs2 + len2);
    for (int i = cs2 + t; i < ce2; i += 256) {
        unsigned int p = bc[i];
        atomicAdd(&dsc[p & 0x3FFu], __uint_as_float(p & 0xffff0000u));
    }
    __syncthreads();
    size_t base = ((size_t)b * 8 + ch) * BUCKET;
    for (int k = t; k < BUCKET; k += 256) {
        subcnt[base + k] = cnt[k];
        subds[base + k]  = ds[k];
        subdsc[base + k] = dsc[k];
    }
}

// ---- combine: per-bucket scan -> rowstart/rowend, per-chunk bases, inv_r, inv_c ----
__global__ __launch_bounds__(1024)
void combine_kernel(int* __restrict__ subcnt, const float* __restrict__ subds,
                    const float* __restrict__ subdsc,
                    int* __restrict__ rowstart, int* __restrict__ rowend,
                    float* __restrict__ inv_r, float* __restrict__ inv_c,
                    int N, int cap) {
    __shared__ int tot[BUCKET];
    int b = blockIdx.x, t = threadIdx.x;
    size_t base = (size_t)b * 8 * BUCKET;
    int c8[8];
    int sum = 0;
    #pragma unroll
    for (int c = 0; c < 8; c++) { c8[c] = subcnt[base + c * BUCKET + t]; sum += c8[c]; }
    tot[t] = sum;
    __syncthreads();
    for (int off = 1; off < BUCKET; off <<= 1) {
        int v = (t >= off) ? tot[t - off] : 0;
        __syncthreads();
        tot[t] += v;
        __syncthreads();
    }
    int excl = tot[t] - sum;
    int node = b * BUCKET + t;
    int s = b * cap;
    if (node < N) {
        rowstart[node] = s + excl;
        rowend[node]   = s + excl + sum;
    }
    int run = s + excl;
    #pragma unroll
    for (int c = 0; c < 8; c++) { int v = c8[c]; subcnt[base + c * BUCKET + t] = run; run += v; }
    float d = 0.0f, dc = 0.0f;
    #pragma unroll
    for (int c = 0; c < 8; c++) { d += subds[base + c * BUCKET + t]; dc += subdsc[base + c * BUCKET + t]; }
    inv_r[b * BUCKET + t] = 1.0f / (sqrtf(d) + 1e-8f);
    inv_c[b * BUCKET + t] = 1.0f / (sqrtf(dc) + 1e-8f);
}

// ---- place: ranked placement; weight folded & stored as f16 bits (low 16 of .y) ----
__global__ __launch_bounds__(256)
void place_kernel(const ull* __restrict__ br, const int* __restrict__ gfill_r,
                  const int* __restrict__ pbase, const float* __restrict__ inv_r,
                  const float* __restrict__ inv_c,
                  int2* __restrict__ cw, int cap) {
    __shared__ int fill[BUCKET];
    __shared__ float irs[BUCKET];
    int b = blockIdx.x >> 3, ch = blockIdx.x & 7;
    int t = threadIdx.x;
    size_t pb = ((size_t)b * 8 + ch) * BUCKET;
    for (int k = t; k < BUCKET; k += 256) {
        fill[k] = pbase[pb + k];
        irs[k]  = inv_r[b * BUCKET + k];
    }
    __syncthreads();
    int s = b * cap;
    int e = gfill_r[b * 16];
    int len = ((e - s) + 7) >> 3;
    int cs = s + ch * len, ce = min(e, cs + len);
    for (int i = cs + t; i < ce; i += 256) {
        ull p = br[i];
        int c = (int)(p & CMASK);
        int lr = (int)((p >> LRSHIFT) & LRMASK);
        float v = __uint_as_float((unsigned)(p >> 32));
        int pos = atomicAdd(&fill[lr], 1);
        float wv = v * inv_c[c] * irs[lr];
        int2 pk;
        pk.x = c;
        pk.y = (int)pk_f16x2(wv, wv);      // f16 weight in low 16
        cw[pos] = pk;
    }
}

// ---- fused: acc = nf (fp32), fb0 = f16(nf) ----
__global__ void cvt_kernel(const float* __restrict__ src, float* __restrict__ acc,
                           unsigned int* __restrict__ dst, long n2) {
    long i = (long)blockIdx.x * blockDim.x + threadIdx.x;
    if (i < n2) {
        float2 v = ((const float2*)src)[i];
        ((float2*)acc)[i] = v;
        dst[i] = pk_f16x2(v.x, v.y);
    }
}

// ---- SpMM: wave per row, edge PAIRS per lane, f16 gather + v_dot2_f32_f16 ----
__global__ __launch_bounds__(256)
void spmm_f16_kernel(const int* __restrict__ rowstart, const int* __restrict__ rowend,
                     const int2* __restrict__ cw,
                     const unsigned short* __restrict__ fin,
                     unsigned short* __restrict__ fout,
                     float* __restrict__ acc, int N) {
    int wid = blockIdx.x * (blockDim.x >> 6) + (threadIdx.x >> 6);   // row
    if (wid >= N) return;
    int lane = threadIdx.x & 63;
    int g = lane >> 3;          // edge-pair slot 0..7 (16 edges per iteration)
    int h = lane & 7;           // feature chunk (8 f16 = 16 B)
    int s = rowstart[wid], e = rowend[wid];
    float a[8];
    #pragma unroll
    for (int k = 0; k < 8; k++) a[k] = 0.0f;

    int nfull = (e - s) >> 4;
    int base = s;
    for (int it = 0; it < nfull; it++, base += 16) {
        int j0 = base + 2 * g;
        int2 p0 = cw[j0];
        int2 p1 = cw[j0 + 1];
        uint4 q0 = ((const uint4*)(fin + ((long)p0.x << 6)))[h];
        uint4 q1 = ((const uint4*)(fin + ((long)p1.x << 6)))[h];
        half2_t wp = __builtin_bit_cast(half2_t,
            __builtin_amdgcn_perm((unsigned)p1.y, (unsigned)p0.y, 0x05040100u));
        #define DOT(idx, qa, qb) \
            a[idx]   = __builtin_amdgcn_fdot2(__builtin_bit_cast(half2_t, \
                        __builtin_amdgcn_perm(qb, qa, 0x05040100u)), wp, a[idx], false); \
            a[idx+1] = __builtin_amdgcn_fdot2(__builtin_bit_cast(half2_t, \
                        __builtin_amdgcn_perm(qb, qa, 0x07060302u)), wp, a[idx+1], false);
        DOT(0, q0.x, q1.x)
        DOT(2, q0.y, q1.y)
        DOT(4, q0.z, q1.z)
        DOT(6, q0.w, q1.w)
    }
    if (base < e) {
        // tail: overreads hit next row's valid entries (or bucket-end pad);
        // mask weights by validity, clamp col for the pad-poison case.
        int j0 = base + 2 * g, j1 = j0 + 1;
        int2 p0 = cw[j0];
        int2 p1 = cw[j1];
        int c0 = p0.x & CMASK, c1 = p1.x & CMASK;
        unsigned w0 = (j0 < e) ? ((unsigned)p0.y & 0xffffu) : 0u;
        unsigned w1 = (j1 < e) ? ((unsigned)p1.y << 16) : 0u;
        half2_t wp = __builtin_bit_cast(half2_t, w0 | (w1 & 0xffff0000u));
        uint4 q0 = ((const uint4*)(fin + ((long)c0 << 6)))[h];
        uint4 q1 = ((const uint4*)(fin + ((long)c1 << 6)))[h];
        DOT(0, q0.x, q1.x)
        DOT(2, q0.y, q1.y)
        DOT(4, q0.z, q1.z)
        DOT(6, q0.w, q1.w)
        #undef DOT
    }

    // reduce over the 8 pair slots (lane bits 3,4,5)
    #pragma unroll
    for (int k = 0; k < 8; k++) {
        a[k] += __shfl_xor(a[k], 8);
        a[k] += __shfl_xor(a[k], 16);
        a[k] += __shfl_xor(a[k], 32);
    }
    float ss = 0.0f;
    #pragma unroll
    for (int k = 0; k < 8; k++) ss += a[k] * a[k];
    ss += __shfl_xor(ss, 1);
    ss += __shfl_xor(ss, 2);
    ss += __shfl_xor(ss, 4);
    float s2 = 1.0f / fmaxf(sqrtf(ss), 1e-12f);
    if (g == 0) {
        uint4 o;
        o.x = pk_f16x2(a[0], a[1]);
        o.y = pk_f16x2(a[2], a[3]);
        o.z = pk_f16x2(a[4], a[5]);
        o.w = pk_f16x2(a[6], a[7]);
        ((uint4*)(fout + ((long)wid << 6)))[h] = o;
        float4* ap = (float4*)(acc + ((long)wid << 6)) + (h << 1);
        float4 c0 = ap[0], c1 = ap[1];
        c0.x += a[0] * s2; c0.y += a[1] * s2; c0.z += a[2] * s2; c0.w += a[3] * s2;
        c1.x += a[4] * s2; c1.y += a[5] * s2; c1.z += a[6] * s2; c1.w += a[7] * s2;
        ap[0] = c0;
        ap[1] = c1;
    }
}

// ---- BPR loss ----
__global__ void loss_terms_kernel(const float* __restrict__ acc,
                                  const int* __restrict__ a_id, const int* __restrict__ p_id,
                                  const int* __restrict__ n_id,
                                  float* __restrict__ terms, int B) {
    long gid = (long)blockIdx.x * blockDim.x + threadIdx.x;
    int b = (int)(gid >> 6);
    int lane = threadIdx.x & 63;
    if (b < B) {
        int ia = a_id[b], ip = p_id[b], in2 = n_id[b];
        float a = acc[(long)ia * DDIM + lane];
        float p = acc[(long)ip * DDIM + lane];
        float n = acc[(long)in2 * DDIM + lane];
        float dp = a * p, dn = a * n;
        #pragma unroll
        for (int off = 1; off < 64; off <<= 1) { dp += __shfl_xor(dp, off); dn += __shfl_xor(dn, off); }
        if (lane == 0) {
            float x = (dp - dn) * 0.0625f;   // node_rep = acc/4 -> preds scale 1/16
            terms[b] = fmaxf(-x, 0.0f) + log1pf(expf(-fabsf(x)));
        }
    }
}

__global__ void reduce_kernel(const float* __restrict__ terms, float* __restrict__ out, int B) {
    __shared__ float sm[256];
    float s = 0.0f;
    for (int i = threadIdx.x; i < B; i += 256) s += terms[i];
    sm[threadIdx.x] = s;
    __syncthreads();
    for (int stride = 128; stride > 0; stride >>= 1) {
        if (threadIdx.x < stride) sm[threadIdx.x] += sm[threadIdx.x + stride];
        __syncthreads();
    }
    if (threadIdx.x == 0) out[0] = sm[0] / (float)B;
}

extern "C" void kernel_launch(void* const* d_in, const int* in_sizes, int n_in,
                              void* d_out, int out_size, void* d_ws, size_t ws_size,
                              hipStream_t stream) {
    const float* nf    = (const float*)d_in[0];
    const int*   erow  = (const int*)d_in[1];
    const int*   ecol  = (const int*)d_in[2];
    const float* evals = (const float*)d_in[3];
    const int*   a_id  = (const int*)d_in[4];
    const int*   p_id  = (const int*)d_in[5];
    const int*   n_id  = (const int*)d_in[6];

    int N = in_sizes[0] / DDIM;
    int E = in_sizes[1];
    int B = in_sizes[4];
    int NB = (N + BUCKET - 1) / BUCKET;
    int chunk = (E + NBLK - 1) / NBLK;
    int Npad = NB * BUCKET;

    long capl = ((long)E * BUCKET) / N;
    int cap = (int)(capl + capl / 12 + 1024);
    cap = (cap + 63) & ~63;

    size_t regionBytes = (size_t)cap * NB * 8;
    size_t featB32 = (size_t)N * DDIM * 4;
    size_t featB16 = (size_t)N * DDIM * 2;
    size_t subBytes = (size_t)NB * 8 * BUCKET * 4;

    char* w = (char*)d_ws;
    ull*  br     = (ull*)w;           // region A: later fb0+fb1
    char* regAp  = w;                 w += regionBytes;
    unsigned int* bc = (unsigned int*)w;  // region B: bc (4 B), later cw (8 B)
    int2* cw     = (int2*)w;          w += regionBytes;
    float* acc   = (float*)w;         w += featB32;
    int* subcnt  = (int*)w;           w += subBytes;    // becomes pbase in combine
    float* subds = (float*)w;         w += subBytes;
    float* subdsc= (float*)w;         w += subBytes;
    float* inv_c = (float*)w;         w += (size_t)Npad * 4;
    float* inv_r = (float*)w;         w += (size_t)Npad * 4;
    int* rowstart= (int*)w;           w += (size_t)N * 4;
    int* rowend  = (int*)w;           w += (size_t)N * 4;
    int* gfill_r = (int*)w;           w += (size_t)NB * 16 * 4;
    int* gfill_c = (int*)w;           w += (size_t)NB * 16 * 4;
    float* terms = (float*)w;         w += (size_t)B * 4;

    unsigned short* fb0 = (unsigned short*)regAp;             // aliases br (dead after place)
    unsigned short* fb1 = (unsigned short*)(regAp + featB16);

    init_fill_kernel<<<1, 128, 0, stream>>>(gfill_r, gfill_c, NB, cap);
    binning_kernel<<<NBLK, TPB_BIN, 0, stream>>>(erow, ecol, evals, gfill_r, gfill_c,
                                                 br, bc, E, NB, chunk);
    count_kernel<<<NB * 8, 256, 0, stream>>>(br, bc, gfill_r, gfill_c,
                                             subcnt, subds, subdsc, cap);
    combine_kernel<<<NB, 1024, 0, stream>>>(subcnt, subds, subdsc, rowstart, rowend,
                                            inv_r, inv_c, N, cap);
    place_kernel<<<NB * 8, 256, 0, stream>>>(br, gfill_r, subcnt, inv_r, inv_c, cw, cap);

    long n2 = (long)N * DDIM / 2;
    cvt_kernel<<<(unsigned)((n2 + 255) / 256), 256, 0, stream>>>(nf, acc, (unsigned int*)fb0, n2);

    unsigned spmmGrid = (unsigned)((N + 3) / 4);   // 4 waves (rows) per 256-thread block
    spmm_f16_kernel<<<spmmGrid, 256, 0, stream>>>(rowstart, rowend, cw, fb0, fb1, acc, N);
    spmm_f16_kernel<<<spmmGrid, 256, 0, stream>>>(rowstart, rowend, cw, fb1, fb0, acc, N);
    spmm_f16_kernel<<<spmmGrid, 256, 0, stream>>>(rowstart, rowend, cw, fb0, fb1, acc, N);

    loss_terms_kernel<<<(unsigned)(((long)B * 64 + 255) / 256), 256, 0, stream>>>(
        acc, a_id, p_id, n_id, terms, B);
    reduce_kernel<<<1, 256, 0, stream>>>(terms, (float*)d_out, B);
}